// Round 4
// baseline (147.208 us; speedup 1.0000x reference)
//
#include <hip/hip_runtime.h>

#define N_GROUPS 4096
#define K_POS 4
#define HID 256
#define M_NEG 256
#define KDIM 768  // (K_POS-1)*HID
#define N_EMB (N_GROUPS * K_POS)

typedef __attribute__((ext_vector_type(8))) short bf16x8;
typedef __attribute__((ext_vector_type(4))) float f32x4;
typedef __attribute__((ext_vector_type(4))) uint u32x4;

__device__ inline ushort f2bf(float f) {
  uint x = __float_as_uint(f);
  return (ushort)((x + 0x7fffu + ((x >> 16) & 1u)) >> 16);
}
__device__ inline float bf2f(ushort u) { return __uint_as_float(((uint)u) << 16); }

// dot of 8 bf16 (packed in u32x4) with 8 f32 p[0..7], accumulated into acc
__device__ inline void fma8(const u32x4 a, const float* __restrict__ p, float& acc) {
#pragma unroll
  for (int d = 0; d < 4; ++d) {
    const uint u = a[d];
    acc = fmaf(__uint_as_float(u << 16), p[2 * d], acc);
    acc = fmaf(__uint_as_float(u & 0xffff0000u), p[2 * d + 1], acc);
  }
}

// ---------------- Kernel 0: fp32 -> bf16 for emb and W ----------------
#define N4_EMB (N_EMB * HID / 4)
#define N4_W   (KDIM * HID / 4)
__global__ __launch_bounds__(256) void to_bf16(
    const float* __restrict__ emb, const float* __restrict__ W,
    ushort* __restrict__ embB, ushort* __restrict__ WB) {
  const int i = blockIdx.x * 256 + threadIdx.x;
  if (i < N4_EMB) {
    const float4 v = ((const float4*)emb)[i];
    ushort4 o = {f2bf(v.x), f2bf(v.y), f2bf(v.z), f2bf(v.w)};
    ((ushort4*)embB)[i] = o;
  } else if (i < N4_EMB + N4_W) {
    const int j = i - N4_EMB;
    const float4 v = ((const float4*)W)[j];
    ushort4 o = {f2bf(v.x), f2bf(v.y), f2bf(v.z), f2bf(v.w)};
    ((ushort4*)WB)[j] = o;
  }
}

// ---------------- Kernel 1: predicts = hist_x @ W^T + b (MFMA, f32 out) ----------------
__global__ __launch_bounds__(256) void gemm_mfma(
    const ushort* __restrict__ embB, const ushort* __restrict__ WB,
    const float* __restrict__ bias, float* __restrict__ pred) {
  const int wv = threadIdx.x >> 6, l = threadIdx.x & 63;
  const int mt = blockIdx.x * 4 + wv;
  const int bn = blockIdx.y * 64;
  const int r = l & 15, g = l >> 4;

  const short* A = (const short*)embB + (size_t)(mt * 16 + r) * (K_POS * HID) + g * 8;
  f32x4 acc[4] = {{0,0,0,0},{0,0,0,0},{0,0,0,0},{0,0,0,0}};
  for (int k0 = 0; k0 < KDIM; k0 += 32) {
    const bf16x8 a = *(const bf16x8*)(A + k0);
#pragma unroll
    for (int j = 0; j < 4; ++j) {
      const bf16x8 b = *(const bf16x8*)((const short*)WB + (size_t)(bn + j * 16 + r) * KDIM + g * 8 + k0);
      acc[j] = __builtin_amdgcn_mfma_f32_16x16x32_bf16(a, b, acc[j], 0, 0, 0);
    }
  }
#pragma unroll
  for (int j = 0; j < 4; ++j) {
    const int col = bn + j * 16 + r;
    const float bb = bias[col];
#pragma unroll
    for (int i = 0; i < 4; ++i)
      pred[(size_t)(mt * 16 + g * 4 + i) * HID + col] = acc[j][i] + bb;
  }
}

// ---------------- Kernel 2: per-row loss; lane owns 4 negatives; 2-stage pipeline ----
__global__ __launch_bounds__(256) void loss_rows(
    const ushort* __restrict__ embB, const float* __restrict__ pred,
    const int* __restrict__ neg_perm, float* __restrict__ row_loss) {
  const int tid = threadIdx.x;
  const int lane = tid & 63, wv = tid >> 6;
  const int n = blockIdx.x * 4 + wv;  // wave owns row n (waves independent, no LDS)

  // positive logit: lane covers elems [lane*4, lane*4+4)  (64*4 = 256 exactly)
  float posv;
  {
    const ushort4 h = *(const ushort4*)(embB + ((size_t)n * K_POS + K_POS - 1) * HID + lane * 4);
    const float4 pv = *(const float4*)(pred + (size_t)n * HID + lane * 4);
    float s = bf2f(h.x) * pv.x + bf2f(h.y) * pv.y + bf2f(h.z) * pv.z + bf2f(h.w) * pv.w;
    s += __shfl_xor(s, 1);  s += __shfl_xor(s, 2);  s += __shfl_xor(s, 4);
    s += __shfl_xor(s, 8);  s += __shfl_xor(s, 16); s += __shfl_xor(s, 32);
    posv = s;
  }

  // lane owns negatives 4*lane .. 4*lane+3 of row n
  const int4 raw = *(const int4*)(neg_perm + (size_t)n * M_NEG + lane * 4);
  const int base = n * K_POS;
  const ushort* rp[4];
  rp[0] = embB + (size_t)(raw.x + (raw.x >= base ? K_POS : 0)) * HID;
  rp[1] = embB + (size_t)(raw.y + (raw.y >= base ? K_POS : 0)) * HID;
  rp[2] = embB + (size_t)(raw.z + (raw.z >= base ? K_POS : 0)) * HID;
  rp[3] = embB + (size_t)(raw.w + (raw.w >= base ? K_POS : 0)) * HID;

  const float4* gp = (const float4*)(pred + (size_t)n * HID);  // wave-uniform pred row

  float ac0 = 0.f, ac1 = 0.f, ac2 = 0.f, ac3 = 0.f;
  u32x4 A[4][4], B[4][4];  // [row][q], statically indexed only

#define LD(BUF, C)                                              \
  {                                                             \
    _Pragma("unroll") for (int r_ = 0; r_ < 4; ++r_)            \
        _Pragma("unroll") for (int q_ = 0; q_ < 4; ++q_)        \
            BUF[r_][q_] = *(const u32x4*)(rp[r_] + (C) + 8 * q_); \
  }
#define CP(BUF, C)                                              \
  {                                                             \
    _Pragma("unroll") for (int q_ = 0; q_ < 4; ++q_) {          \
      const float4 v0 = gp[(C) / 4 + 2 * q_];                   \
      const float4 v1 = gp[(C) / 4 + 2 * q_ + 1];               \
      const float p_[8] = {v0.x, v0.y, v0.z, v0.w, v1.x, v1.y, v1.z, v1.w}; \
      fma8(BUF[0][q_], p_, ac0);                                \
      fma8(BUF[1][q_], p_, ac1);                                \
      fma8(BUF[2][q_], p_, ac2);                                \
      fma8(BUF[3][q_], p_, ac3);                                \
    }                                                           \
  }

  LD(A, 0);
#pragma unroll 1
  for (int c = 0; c < HID - 64; c += 64) {
    LD(B, c + 32);
    CP(A, c);
    LD(A, c + 64);
    CP(B, c + 32);
  }
  // peeled tail: c = HID-64
  LD(B, HID - 32);
  CP(A, HID - 64);
  CP(B, HID - 32);
#undef LD
#undef CP

  // wave-level logsumexp
  float mx = fmaxf(fmaxf(ac0, ac1), fmaxf(ac2, ac3));
  mx = fmaxf(mx, __shfl_xor(mx, 1));  mx = fmaxf(mx, __shfl_xor(mx, 2));
  mx = fmaxf(mx, __shfl_xor(mx, 4));  mx = fmaxf(mx, __shfl_xor(mx, 8));
  mx = fmaxf(mx, __shfl_xor(mx, 16)); mx = fmaxf(mx, __shfl_xor(mx, 32));
  const float gmx = fmaxf(mx, posv);

  float se = __expf(ac0 - gmx) + __expf(ac1 - gmx) + __expf(ac2 - gmx) + __expf(ac3 - gmx);
  se += __shfl_xor(se, 1);  se += __shfl_xor(se, 2);  se += __shfl_xor(se, 4);
  se += __shfl_xor(se, 8);  se += __shfl_xor(se, 16); se += __shfl_xor(se, 32);

  if (lane == 0) row_loss[n] = __logf(se + __expf(posv - gmx)) + gmx - posv;
}

// ---------------- Kernel 3: deterministic mean ----------------
__global__ __launch_bounds__(256) void reduce_mean(
    const float* __restrict__ row_loss, float* __restrict__ out) {
  const int tid = threadIdx.x;
  const int lane = tid & 63, wv = tid >> 6;
  float s = 0.f;
  for (int i = tid; i < N_GROUPS; i += 256) s += row_loss[i];
  s += __shfl_xor(s, 1);  s += __shfl_xor(s, 2);  s += __shfl_xor(s, 4);
  s += __shfl_xor(s, 8);  s += __shfl_xor(s, 16); s += __shfl_xor(s, 32);
  __shared__ float red[4];
  if (lane == 0) red[wv] = s;
  __syncthreads();
  if (tid == 0) out[0] = (red[0] + red[1] + red[2] + red[3]) * (1.0f / N_GROUPS);
}

extern "C" void kernel_launch(void* const* d_in, const int* in_sizes, int n_in,
                              void* d_out, int out_size, void* d_ws, size_t ws_size,
                              hipStream_t stream) {
  const float* emb = (const float*)d_in[0];
  const float* W = (const float*)d_in[1];
  const float* b = (const float*)d_in[2];
  const int* neg_perm = (const int*)d_in[4];
  float* out = (float*)d_out;

  ushort* embB = (ushort*)d_ws;                              // 8 MB
  ushort* WB = embB + (size_t)N_EMB * HID;                   // 0.4 MB
  float* pred = (float*)(WB + (size_t)KDIM * HID);           // 4 MB (f32)
  float* row_loss = pred + (size_t)N_GROUPS * HID;           // 16 KB

  const int n4 = N4_EMB + N4_W;
  to_bf16<<<(n4 + 255) / 256, 256, 0, stream>>>(emb, W, embB, WB);
  gemm_mfma<<<dim3(N_GROUPS / 64, HID / 64), 256, 0, stream>>>(embB, WB, b, pred);
  loss_rows<<<N_GROUPS / 4, 256, 0, stream>>>(embB, pred, neg_perm, row_loss);
  reduce_mean<<<1, 256, 0, stream>>>(row_loss, out);
}